// Round 1
// baseline (31.026 us; speedup 1.0000x reference)
//
#include <hip/hip_runtime.h>

#define BB 8
#define NN 512
#define NOBS 7
#define NF 64
#define ROWS (BB * NN)   // 4096

// ---- kernel 0: global max of norm[0..ROWS) -> ws[0] ----
__global__ void kNormMax(const float* __restrict__ norm, float* __restrict__ ws) {
    __shared__ float s[256];
    float m = 1.0f;  // norm >= 1 by construction
    for (int t = threadIdx.x; t < ROWS; t += 256) m = fmaxf(m, norm[t]);
    s[threadIdx.x] = m;
    __syncthreads();
    for (int off = 128; off > 0; off >>= 1) {
        if ((int)threadIdx.x < off) s[threadIdx.x] = fmaxf(s[threadIdx.x], s[threadIdx.x + off]);
        __syncthreads();
    }
    if (threadIdx.x == 0) ws[0] = s[0];
}

// ---- kernel 1: per-node edge embedding ----
// R[row, k] = relu(W_edge[0,k] + sum_f nf[row,f] * W_edge[1+f,k])  for k<63
// R[row,63] = 0  (padding channel; later replaced by norm/norm_max)
__global__ void kEmbed(const float* __restrict__ nf, const float* __restrict__ We,
                       float* __restrict__ R) {
    int gid = blockIdx.x * 256 + threadIdx.x;
    int row = gid >> 6;        // 0..4095  (= b*N + j)
    int k   = gid & 63;
    float r = 0.0f;
    if (k < 63) {
        float e = We[k];  // W_edge[0, k]
        const float* nfp = nf + row * NOBS;
        #pragma unroll
        for (int f = 0; f < NOBS; ++f) e = fmaf(nfp[f], We[(f + 1) * 63 + k], e);
        r = fmaxf(e, 0.0f);
    }
    R[row * NF + k] = r;
}

// ---- kernel 2: sparse neighbor aggregation + norm channel + output linear ----
// one wave (64 lanes) per (b,i) row; lane = feature channel
__global__ void kAggregate(const float* __restrict__ adj, const float* __restrict__ norm,
                           const float* __restrict__ Wf, const float* __restrict__ ws,
                           float* __restrict__ out) {
    const float* R = ws + 64;
    const float norm_max = ws[0];
    const int w    = threadIdx.x >> 6;
    const int lane = threadIdx.x & 63;
    const int row  = blockIdx.x * 4 + w;       // b*N + i
    const int b    = row >> 9;                 // /512

    const float* adjRow = adj + (size_t)row * NN;
    const float* Rb     = R + (size_t)b * NN * NF;

    float acc = 0.0f;
    #pragma unroll
    for (int g = 0; g < 8; ++g) {
        float a = adjRow[g * 64 + lane];
        unsigned long long m = __ballot(a != 0.0f);   // wave-uniform mask of nonzero j's
        const float* Rg = Rb + (size_t)(g * 64) * NF + lane;
        while (m) {                                   // scalar (wave-uniform) loop
            int bit = __ffsll((long long)m) - 1;
            m &= m - 1;
            acc += Rg[(size_t)bit * NF];              // coalesced 256B gather per j
        }
    }

    const float nrm = norm[row];
    const float x = (lane == 63) ? (nrm / norm_max) : (acc / nrm);

    __shared__ float xs[4][64];
    xs[w][lane] = x;
    __syncthreads();

    // out[row, lane] = relu( sum_k x[k] * W_feat[k, lane] )
    float o = 0.0f;
    #pragma unroll
    for (int k = 0; k < 64; ++k) o = fmaf(xs[w][k], Wf[k * NF + lane], o);
    out[(size_t)row * NF + lane] = fmaxf(o, 0.0f);
}

extern "C" void kernel_launch(void* const* d_in, const int* in_sizes, int n_in,
                              void* d_out, int out_size, void* d_ws, size_t ws_size,
                              hipStream_t stream) {
    const float* nf   = (const float*)d_in[0];  // [8,512,7]
    const float* adj  = (const float*)d_in[1];  // [8,512,512]
    const float* nrm  = (const float*)d_in[2];  // [8,512,1]
    const float* We   = (const float*)d_in[3];  // [8,63]
    const float* Wf   = (const float*)d_in[4];  // [64,64]
    float* out = (float*)d_out;                 // [8,512,64]
    float* ws  = (float*)d_ws;                  // [0]: norm_max, [64..]: R (4096*64 floats)

    kNormMax<<<1, 256, 0, stream>>>(nrm, ws);
    kEmbed<<<(ROWS * NF) / 256, 256, 0, stream>>>(nf, We, ws + 64);
    kAggregate<<<ROWS / 4, 256, 0, stream>>>(adj, nrm, Wf, ws, out);
}

// Round 2
// 25.775 us; speedup vs baseline: 1.2038x; 1.2038x over previous
//
#include <hip/hip_runtime.h>

#define ROWS 4096   // B*N
#define NN   512
#define NF   64

// One wave per output row (b,i). lane = output channel k.
// Fully fused: norm_max (block-redundant) + lazy per-edge embedding + sparse
// aggregation + norm channel + output GEMV.
__global__ __launch_bounds__(256, 4) void kFused(
    const float* __restrict__ nf,   // [8,512,7]
    const float* __restrict__ adj,  // [8,512,512]
    const float* __restrict__ norm, // [8,512,1]
    const float* __restrict__ We,   // [8,63]
    const float* __restrict__ Wf,   // [64,64]
    float* __restrict__ out)        // [8,512,64]
{
    const int tid  = threadIdx.x;
    const int w    = tid >> 6;
    const int lane = tid & 63;
    const int row  = blockIdx.x * 4 + w;   // b*512 + i
    const int b    = row >> 9;

    // --- W_edge column for k = lane (lane 63 -> all zeros => relu(0)=0) ---
    float wb = 0.f, wcol[7];
    if (lane < 63) {
        wb = We[lane];
        #pragma unroll
        for (int f = 0; f < 7; ++f) wcol[f] = We[(f + 1) * 63 + lane];
    } else {
        #pragma unroll
        for (int f = 0; f < 7; ++f) wcol[f] = 0.f;
    }

    // --- block-redundant norm_max over all 4096 rows ---
    __shared__ float sred[4];
    __shared__ float xs[4][64];
    float m = 1.0f;
    for (int t = tid; t < ROWS; t += 256) m = fmaxf(m, norm[t]);
    #pragma unroll
    for (int off = 32; off; off >>= 1) m = fmaxf(m, __shfl_xor(m, off, 64));
    if (lane == 0) sred[w] = m;
    __syncthreads();
    const float norm_max = fmaxf(fmaxf(sred[0], sred[1]), fmaxf(sred[2], sred[3]));

    // --- neighbor masks for this row (wave-uniform, live in SGPRs) ---
    const float* adjRow = adj + (size_t)row * NN;
    unsigned long long mask[8];
    #pragma unroll
    for (int g = 0; g < 8; ++g) mask[g] = __ballot(adjRow[g * 64 + lane] != 0.f);

    const float* nfb = nf + (size_t)b * NN * 7;

    // --- sparse aggregation with lazy embedding, 4 independent chains/iter ---
    float acc = 0.f;
    #pragma unroll
    for (int g = 0; g < 8; ++g) {
        unsigned long long mm = mask[g];
        const float* nfg = nfb + (size_t)(g * 64) * 7;
        while (mm) {
            int b0 = __ffsll((long long)mm) - 1; mm &= mm - 1;
            const bool h1 = (mm != 0);
            int b1 = h1 ? __ffsll((long long)mm) - 1 : b0; if (h1) mm &= mm - 1;
            const bool h2 = (mm != 0);
            int b2 = h2 ? __ffsll((long long)mm) - 1 : b0; if (h2) mm &= mm - 1;
            const bool h3 = (mm != 0);
            int b3 = h3 ? __ffsll((long long)mm) - 1 : b0; if (h3) mm &= mm - 1;
            const float* p0 = nfg + b0 * 7;
            const float* p1 = nfg + b1 * 7;
            const float* p2 = nfg + b2 * 7;
            const float* p3 = nfg + b3 * 7;
            float e0 = wb, e1 = wb, e2 = wb, e3 = wb;
            #pragma unroll
            for (int f = 0; f < 7; ++f) {
                e0 = fmaf(p0[f], wcol[f], e0);
                e1 = fmaf(p1[f], wcol[f], e1);
                e2 = fmaf(p2[f], wcol[f], e2);
                e3 = fmaf(p3[f], wcol[f], e3);
            }
            acc += fmaxf(e0, 0.f);
            acc += h1 ? fmaxf(e1, 0.f) : 0.f;
            acc += h2 ? fmaxf(e2, 0.f) : 0.f;
            acc += h3 ? fmaxf(e3, 0.f) : 0.f;
        }
    }

    // --- x vector, then 64x64 output GEMV via LDS broadcast ---
    const float nrm = norm[row];
    const float x = (lane == 63) ? (nrm / norm_max) : (acc / nrm);
    xs[w][lane] = x;
    __syncthreads();

    float o = 0.f;
    #pragma unroll
    for (int k = 0; k < 64; ++k) o = fmaf(xs[w][k], Wf[k * NF + lane], o);
    out[(size_t)row * NF + lane] = fmaxf(o, 0.f);
}

extern "C" void kernel_launch(void* const* d_in, const int* in_sizes, int n_in,
                              void* d_out, int out_size, void* d_ws, size_t ws_size,
                              hipStream_t stream) {
    const float* nf  = (const float*)d_in[0];
    const float* adj = (const float*)d_in[1];
    const float* nrm = (const float*)d_in[2];
    const float* We  = (const float*)d_in[3];
    const float* Wf  = (const float*)d_in[4];
    float* out = (float*)d_out;

    kFused<<<ROWS / 4, 256, 0, stream>>>(nf, adj, nrm, We, Wf, out);
}

// Round 3
// 15.671 us; speedup vs baseline: 1.9799x; 1.6448x over previous
//
#include <hip/hip_runtime.h>

#define ROWS 4096   // B*N
#define NN   512
#define NF   64

// One wave per output row (b,i), lane = output channel k. 4 rows per block.
// nf[b] staged in LDS (padded to 8 f32/row) -> edge loop is LDS-latency, not L2.
__global__ __launch_bounds__(256, 8) void kFused(
    const float* __restrict__ nf,   // [8,512,7]
    const float* __restrict__ adj,  // [8,512,512]
    const float* __restrict__ norm, // [8,512,1]
    const float* __restrict__ We,   // [8,63]
    const float* __restrict__ Wf,   // [64,64]
    float* __restrict__ out)        // [8,512,64]
{
    const int tid  = threadIdx.x;
    const int w    = tid >> 6;
    const int lane = tid & 63;
    const int row  = blockIdx.x * 4 + w;   // b*512 + i
    const int b    = row >> 9;

    __shared__ float nf_s[NN * 8];   // 16 KB, row-padded to 8
    __shared__ float sred[4];
    __shared__ float xs[4][64];

    // --- stage nf[b] into LDS (coalesced global read) ---
    const float* nfb = nf + (size_t)b * NN * 7;
    #pragma unroll
    for (int it = 0; it < 14; ++it) {
        int idx = it * 256 + tid;            // 0..3583
        int j = idx / 7;                     // magic-mul div
        int f = idx - j * 7;
        nf_s[j * 8 + f] = nfb[idx];
    }

    // --- W_edge column for k = lane (lane 63 -> zeros) ---
    float wb = 0.f, wcol[7];
    if (lane < 63) {
        wb = We[lane];
        #pragma unroll
        for (int f = 0; f < 7; ++f) wcol[f] = We[(f + 1) * 63 + lane];
    } else {
        #pragma unroll
        for (int f = 0; f < 7; ++f) wcol[f] = 0.f;
    }

    // --- norm_max over all 4096 rows (block-redundant, float4) ---
    float m = 1.0f;
    const float4* n4 = (const float4*)norm;
    #pragma unroll
    for (int q = 0; q < 4; ++q) {
        float4 v = n4[q * 256 + tid];
        m = fmaxf(fmaxf(m, v.x), fmaxf(v.y, fmaxf(v.z, v.w)));
    }
    #pragma unroll
    for (int off = 32; off; off >>= 1) m = fmaxf(m, __shfl_xor(m, off, 64));
    if (lane == 0) sred[w] = m;

    // --- neighbor masks via float4 adj reads; mask[q*4+c] bit l <-> j = q*256 + 4l + c ---
    const float4* a4 = (const float4*)(adj + (size_t)row * NN);
    unsigned long long mask[8];
    #pragma unroll
    for (int q = 0; q < 2; ++q) {
        float4 v = a4[q * 64 + lane];
        mask[q * 4 + 0] = __ballot(v.x != 0.f);
        mask[q * 4 + 1] = __ballot(v.y != 0.f);
        mask[q * 4 + 2] = __ballot(v.z != 0.f);
        mask[q * 4 + 3] = __ballot(v.w != 0.f);
    }

    __syncthreads();   // nf_s + sred ready
    const float norm_max = fmaxf(fmaxf(sred[0], sred[1]), fmaxf(sred[2], sred[3]));

    // --- sparse aggregation; lazy embed from LDS, 4 independent edges/iter ---
    float acc = 0.f;
    #pragma unroll
    for (int q = 0; q < 2; ++q) {
        #pragma unroll
        for (int c = 0; c < 4; ++c) {
            unsigned long long mm = mask[q * 4 + c];
            const float* base = nf_s + (size_t)q * 256 * 8 + c * 8;  // + bit*32
            while (mm) {
                int b0 = __ffsll((long long)mm) - 1; mm &= mm - 1;
                const bool h1 = (mm != 0);
                int b1 = h1 ? __ffsll((long long)mm) - 1 : b0; if (h1) mm &= mm - 1;
                const bool h2 = (mm != 0);
                int b2 = h2 ? __ffsll((long long)mm) - 1 : b0; if (h2) mm &= mm - 1;
                const bool h3 = (mm != 0);
                int b3 = h3 ? __ffsll((long long)mm) - 1 : b0; if (h3) mm &= mm - 1;
                const float4 lo0 = *(const float4*)(base + b0 * 32);
                const float4 hi0 = *(const float4*)(base + b0 * 32 + 4);
                const float4 lo1 = *(const float4*)(base + b1 * 32);
                const float4 hi1 = *(const float4*)(base + b1 * 32 + 4);
                const float4 lo2 = *(const float4*)(base + b2 * 32);
                const float4 hi2 = *(const float4*)(base + b2 * 32 + 4);
                const float4 lo3 = *(const float4*)(base + b3 * 32);
                const float4 hi3 = *(const float4*)(base + b3 * 32 + 4);
                float e0 = wb, e1 = wb, e2 = wb, e3 = wb;
                e0 = fmaf(lo0.x, wcol[0], e0); e0 = fmaf(lo0.y, wcol[1], e0);
                e0 = fmaf(lo0.z, wcol[2], e0); e0 = fmaf(lo0.w, wcol[3], e0);
                e0 = fmaf(hi0.x, wcol[4], e0); e0 = fmaf(hi0.y, wcol[5], e0);
                e0 = fmaf(hi0.z, wcol[6], e0);
                e1 = fmaf(lo1.x, wcol[0], e1); e1 = fmaf(lo1.y, wcol[1], e1);
                e1 = fmaf(lo1.z, wcol[2], e1); e1 = fmaf(lo1.w, wcol[3], e1);
                e1 = fmaf(hi1.x, wcol[4], e1); e1 = fmaf(hi1.y, wcol[5], e1);
                e1 = fmaf(hi1.z, wcol[6], e1);
                e2 = fmaf(lo2.x, wcol[0], e2); e2 = fmaf(lo2.y, wcol[1], e2);
                e2 = fmaf(lo2.z, wcol[2], e2); e2 = fmaf(lo2.w, wcol[3], e2);
                e2 = fmaf(hi2.x, wcol[4], e2); e2 = fmaf(hi2.y, wcol[5], e2);
                e2 = fmaf(hi2.z, wcol[6], e2);
                e3 = fmaf(lo3.x, wcol[0], e3); e3 = fmaf(lo3.y, wcol[1], e3);
                e3 = fmaf(lo3.z, wcol[2], e3); e3 = fmaf(lo3.w, wcol[3], e3);
                e3 = fmaf(hi3.x, wcol[4], e3); e3 = fmaf(hi3.y, wcol[5], e3);
                e3 = fmaf(hi3.z, wcol[6], e3);
                acc += fmaxf(e0, 0.f);
                acc += h1 ? fmaxf(e1, 0.f) : 0.f;
                acc += h2 ? fmaxf(e2, 0.f) : 0.f;
                acc += h3 ? fmaxf(e3, 0.f) : 0.f;
            }
        }
    }

    // --- x vector; per-wave LDS broadcast (no cross-wave barrier needed) ---
    const float nrm = norm[row];
    const float x = (lane == 63) ? (nrm / norm_max) : (acc / nrm);
    xs[w][lane] = x;

    float o = 0.f;
    #pragma unroll
    for (int k = 0; k < 64; ++k) o = fmaf(xs[w][k], Wf[k * NF + lane], o);
    out[(size_t)row * NF + lane] = fmaxf(o, 0.f);
}

extern "C" void kernel_launch(void* const* d_in, const int* in_sizes, int n_in,
                              void* d_out, int out_size, void* d_ws, size_t ws_size,
                              hipStream_t stream) {
    const float* nf  = (const float*)d_in[0];
    const float* adj = (const float*)d_in[1];
    const float* nrm = (const float*)d_in[2];
    const float* We  = (const float*)d_in[3];
    const float* Wf  = (const float*)d_in[4];
    float* out = (float*)d_out;

    kFused<<<ROWS / 4, 256, 0, stream>>>(nf, adj, nrm, We, Wf, out);
}

// Round 4
// 15.640 us; speedup vs baseline: 1.9837x; 1.0019x over previous
//
#include <hip/hip_runtime.h>

#define ROWS 4096   // B*N
#define NN   512
#define NF   64

// One wave per output row (b,i), lane = output channel k. 4 rows per block.
// nf[b] staged in LDS (row-padded to 8 f32) -> edge loop is LDS-broadcast + FMA.
__global__ __launch_bounds__(256, 4) void kFused(
    const float* __restrict__ nf,   // [8,512,7]
    const float* __restrict__ adj,  // [8,512,512]
    const float* __restrict__ norm, // [8,512,1]
    const float* __restrict__ We,   // [8,63]
    const float* __restrict__ Wf,   // [64,64]
    float* __restrict__ out)        // [8,512,64]
{
    const int tid  = threadIdx.x;
    const int w    = tid >> 6;
    const int lane = tid & 63;
    const int row  = blockIdx.x * 4 + w;   // b*512 + i
    const int b    = row >> 9;

    __shared__ float nf_s[NN * 8];   // 16 KB
    __shared__ float sred[4];
    __shared__ float xs[4][64];

    // --- stage nf[b]: one row per thread, x2 (no div, vector LDS writes) ---
    const float* nfb = nf + (size_t)b * NN * 7;
    #pragma unroll
    for (int rr = 0; rr < 2; ++rr) {
        const int j = tid + rr * 256;
        const float* p = nfb + j * 7;
        float4 lo = make_float4(p[0], p[1], p[2], p[3]);
        float4 hi = make_float4(p[4], p[5], p[6], 0.f);
        *(float4*)&nf_s[j * 8]     = lo;
        *(float4*)&nf_s[j * 8 + 4] = hi;
    }

    // --- W_edge column for k = lane (lane 63 -> zeros) ---
    float wb = 0.f, wcol[7];
    if (lane < 63) {
        wb = We[lane];
        #pragma unroll
        for (int f = 0; f < 7; ++f) wcol[f] = We[(f + 1) * 63 + lane];
    } else {
        #pragma unroll
        for (int f = 0; f < 7; ++f) wcol[f] = 0.f;
    }

    // --- norm_max over all 4096 rows (block-redundant, float4) ---
    float m = 1.0f;
    const float4* n4 = (const float4*)norm;
    #pragma unroll
    for (int q = 0; q < 4; ++q) {
        float4 v = n4[q * 256 + tid];
        m = fmaxf(fmaxf(m, v.x), fmaxf(v.y, fmaxf(v.z, v.w)));
    }
    #pragma unroll
    for (int off = 32; off; off >>= 1) m = fmaxf(m, __shfl_xor(m, off, 64));
    if (lane == 0) sred[w] = m;

    // --- neighbor masks; mask[q*4+c] bit l <-> j = q*256 + 4l + c ---
    const float4* a4 = (const float4*)(adj + (size_t)row * NN);
    unsigned long long mask[8];
    #pragma unroll
    for (int q = 0; q < 2; ++q) {
        float4 v = a4[q * 64 + lane];
        mask[q * 4 + 0] = __ballot(v.x != 0.f);
        mask[q * 4 + 1] = __ballot(v.y != 0.f);
        mask[q * 4 + 2] = __ballot(v.z != 0.f);
        mask[q * 4 + 3] = __ballot(v.w != 0.f);
    }

    const float nrm = norm[row];

    __syncthreads();   // nf_s + sred ready
    const float norm_max = fmaxf(fmaxf(sred[0], sred[1]), fmaxf(sred[2], sred[3]));

    // --- sparse aggregation; lazy embed from LDS, 4 independent edges/iter ---
    float acc = 0.f;
    #pragma unroll
    for (int q = 0; q < 2; ++q) {
        #pragma unroll
        for (int c = 0; c < 4; ++c) {
            unsigned long long mm = mask[q * 4 + c];
            const float* base = nf_s + (size_t)q * 256 * 8 + c * 8;  // + bit*32
            while (mm) {
                int b0 = __ffsll((long long)mm) - 1; mm &= mm - 1;
                const bool h1 = (mm != 0);
                int b1 = h1 ? __ffsll((long long)mm) - 1 : b0; if (h1) mm &= mm - 1;
                const bool h2 = (mm != 0);
                int b2 = h2 ? __ffsll((long long)mm) - 1 : b0; if (h2) mm &= mm - 1;
                const bool h3 = (mm != 0);
                int b3 = h3 ? __ffsll((long long)mm) - 1 : b0; if (h3) mm &= mm - 1;
                const float4 lo0 = *(const float4*)(base + b0 * 32);
                const float4 hi0 = *(const float4*)(base + b0 * 32 + 4);
                const float4 lo1 = *(const float4*)(base + b1 * 32);
                const float4 hi1 = *(const float4*)(base + b1 * 32 + 4);
                const float4 lo2 = *(const float4*)(base + b2 * 32);
                const float4 hi2 = *(const float4*)(base + b2 * 32 + 4);
                const float4 lo3 = *(const float4*)(base + b3 * 32);
                const float4 hi3 = *(const float4*)(base + b3 * 32 + 4);
                float e0 = wb, e1 = wb, e2 = wb, e3 = wb;
                e0 = fmaf(lo0.x, wcol[0], e0); e0 = fmaf(lo0.y, wcol[1], e0);
                e0 = fmaf(lo0.z, wcol[2], e0); e0 = fmaf(lo0.w, wcol[3], e0);
                e0 = fmaf(hi0.x, wcol[4], e0); e0 = fmaf(hi0.y, wcol[5], e0);
                e0 = fmaf(hi0.z, wcol[6], e0);
                e1 = fmaf(lo1.x, wcol[0], e1); e1 = fmaf(lo1.y, wcol[1], e1);
                e1 = fmaf(lo1.z, wcol[2], e1); e1 = fmaf(lo1.w, wcol[3], e1);
                e1 = fmaf(hi1.x, wcol[4], e1); e1 = fmaf(hi1.y, wcol[5], e1);
                e1 = fmaf(hi1.z, wcol[6], e1);
                e2 = fmaf(lo2.x, wcol[0], e2); e2 = fmaf(lo2.y, wcol[1], e2);
                e2 = fmaf(lo2.z, wcol[2], e2); e2 = fmaf(lo2.w, wcol[3], e2);
                e2 = fmaf(hi2.x, wcol[4], e2); e2 = fmaf(hi2.y, wcol[5], e2);
                e2 = fmaf(hi2.z, wcol[6], e2);
                e3 = fmaf(lo3.x, wcol[0], e3); e3 = fmaf(lo3.y, wcol[1], e3);
                e3 = fmaf(lo3.z, wcol[2], e3); e3 = fmaf(lo3.w, wcol[3], e3);
                e3 = fmaf(hi3.x, wcol[4], e3); e3 = fmaf(hi3.y, wcol[5], e3);
                e3 = fmaf(hi3.z, wcol[6], e3);
                acc += fmaxf(e0, 0.f);
                acc += h1 ? fmaxf(e1, 0.f) : 0.f;
                acc += h2 ? fmaxf(e2, 0.f) : 0.f;
                acc += h3 ? fmaxf(e3, 0.f) : 0.f;
            }
        }
    }

    // --- x vector; per-wave LDS broadcast (no cross-wave barrier needed) ---
    const float x = (lane == 63) ? (nrm / norm_max) : (acc / nrm);
    xs[w][lane] = x;

    // --- out[row, lane] = relu( sum_k x[k] * W_feat[k, lane] ), xs via f4 ---
    float o = 0.f;
    #pragma unroll
    for (int k4 = 0; k4 < 16; ++k4) {
        float4 xv = *(const float4*)&xs[w][k4 * 4];
        o = fmaf(xv.x, Wf[(k4 * 4 + 0) * NF + lane], o);
        o = fmaf(xv.y, Wf[(k4 * 4 + 1) * NF + lane], o);
        o = fmaf(xv.z, Wf[(k4 * 4 + 2) * NF + lane], o);
        o = fmaf(xv.w, Wf[(k4 * 4 + 3) * NF + lane], o);
    }
    out[(size_t)row * NF + lane] = fmaxf(o, 0.f);
}

extern "C" void kernel_launch(void* const* d_in, const int* in_sizes, int n_in,
                              void* d_out, int out_size, void* d_ws, size_t ws_size,
                              hipStream_t stream) {
    const float* nf  = (const float*)d_in[0];
    const float* adj = (const float*)d_in[1];
    const float* nrm = (const float*)d_in[2];
    const float* We  = (const float*)d_in[3];
    const float* Wf  = (const float*)d_in[4];
    float* out = (float*)d_out;

    kFused<<<ROWS / 4, 256, 0, stream>>>(nf, adj, nrm, We, Wf, out);
}

// Round 5
// 15.515 us; speedup vs baseline: 1.9997x; 1.0081x over previous
//
#include <hip/hip_runtime.h>

#define ROWS 4096   // B*N
#define NN   512
#define NF   64

// One wave per output row (b,i), lane = output channel k. 4 rows per block.
// Edge indices compacted to an LDS u16 list via mbcnt (parallel), then the
// aggregation loop processes 8 edges/iter with independent FMA chains.
__global__ __launch_bounds__(256, 4) void kFused(
    const float* __restrict__ nf,   // [8,512,7]
    const float* __restrict__ adj,  // [8,512,512]
    const float* __restrict__ norm, // [8,512,1]
    const float* __restrict__ We,   // [8,63]
    const float* __restrict__ Wf,   // [64,64]
    float* __restrict__ out)        // [8,512,64]
{
    const int tid  = threadIdx.x;
    const int w    = tid >> 6;
    const int lane = tid & 63;
    const int row  = blockIdx.x * 4 + w;   // b*512 + i
    const int b    = row >> 9;

    __shared__ float nf_s[NN * 8];              // 16 KB
    __shared__ unsigned short lists[4][520];    // 512 + 8 pad per row (bulletproof)
    __shared__ float sred[4];
    __shared__ float xs[4][64];

    // --- stage nf[b]: one row per thread, x2 ---
    const float* nfb = nf + (size_t)b * NN * 7;
    #pragma unroll
    for (int rr = 0; rr < 2; ++rr) {
        const int j = tid + rr * 256;
        const float* p = nfb + j * 7;
        float4 lo = make_float4(p[0], p[1], p[2], p[3]);
        float4 hi = make_float4(p[4], p[5], p[6], 0.f);
        *(float4*)&nf_s[j * 8]     = lo;
        *(float4*)&nf_s[j * 8 + 4] = hi;
    }

    // --- W_edge column for k = lane (lane 63 -> zeros) ---
    float wb = 0.f, wcol[7];
    if (lane < 63) {
        wb = We[lane];
        #pragma unroll
        for (int f = 0; f < 7; ++f) wcol[f] = We[(f + 1) * 63 + lane];
    } else {
        #pragma unroll
        for (int f = 0; f < 7; ++f) wcol[f] = 0.f;
    }

    // --- norm_max over all 4096 rows (block-redundant, float4) ---
    float m = 1.0f;
    const float4* n4 = (const float4*)norm;
    #pragma unroll
    for (int q = 0; q < 4; ++q) {
        float4 v = n4[q * 256 + tid];
        m = fmaxf(fmaxf(m, v.x), fmaxf(v.y, fmaxf(v.z, v.w)));
    }
    #pragma unroll
    for (int off = 32; off; off >>= 1) m = fmaxf(m, __shfl_xor(m, off, 64));
    if (lane == 0) sred[w] = m;

    // --- adj row -> compacted edge list in LDS (parallel, mbcnt-based) ---
    const float4* a4 = (const float4*)(adj + (size_t)row * NN);
    unsigned int cnt = 0;
    #pragma unroll
    for (int q = 0; q < 2; ++q) {
        float4 v = a4[q * 64 + lane];
        float comp[4] = {v.x, v.y, v.z, v.w};
        #pragma unroll
        for (int c = 0; c < 4; ++c) {
            unsigned long long mm = __ballot(comp[c] != 0.f);
            unsigned int pos = __builtin_amdgcn_mbcnt_hi(
                (unsigned int)(mm >> 32),
                __builtin_amdgcn_mbcnt_lo((unsigned int)mm, 0u));
            if (comp[c] != 0.f)
                lists[w][cnt + pos] = (unsigned short)(q * 256 + 4 * lane + c);
            cnt += (unsigned int)__popcll(mm);
        }
    }
    if (lane < 8) lists[w][cnt + lane] = 0;   // pad so last 8-batch reads valid row 0

    const float nrm = norm[row];

    __syncthreads();   // nf_s + sred ready
    const float norm_max = fmaxf(fmaxf(sred[0], sred[1]), fmaxf(sred[2], sred[3]));

    // --- aggregation: 8 edges/iter, independent chains, uniform tail mask ---
    float acc = 0.f;
    const int niter = (int)((cnt + 7u) >> 3);
    for (int itn = 0; itn < niter; ++itn) {
        const int e0 = itn * 8;
        const uint4 lw = *(const uint4*)&lists[w][e0];   // 8 u16, broadcast read
        int j[8];
        j[0] = (int)(lw.x & 0xffffu); j[1] = (int)(lw.x >> 16);
        j[2] = (int)(lw.y & 0xffffu); j[3] = (int)(lw.y >> 16);
        j[4] = (int)(lw.z & 0xffffu); j[5] = (int)(lw.z >> 16);
        j[6] = (int)(lw.w & 0xffffu); j[7] = (int)(lw.w >> 16);
        float e[8];
        #pragma unroll
        for (int s = 0; s < 8; ++s) {
            const float4 lo = *(const float4*)&nf_s[j[s] * 8];
            const float4 hi = *(const float4*)&nf_s[j[s] * 8 + 4];
            float ee = wb;
            ee = fmaf(lo.x, wcol[0], ee); ee = fmaf(lo.y, wcol[1], ee);
            ee = fmaf(lo.z, wcol[2], ee); ee = fmaf(lo.w, wcol[3], ee);
            ee = fmaf(hi.x, wcol[4], ee); ee = fmaf(hi.y, wcol[5], ee);
            ee = fmaf(hi.z, wcol[6], ee);
            e[s] = ee;
        }
        #pragma unroll
        for (int s = 0; s < 8; ++s) {
            const float ms = ((unsigned)(e0 + s) < cnt) ? 1.f : 0.f;  // wave-uniform
            acc = fmaf(ms, fmaxf(e[s], 0.f), acc);
        }
    }

    // --- x vector; per-wave LDS broadcast ---
    const float x = (lane == 63) ? (nrm / norm_max) : (acc / nrm);
    xs[w][lane] = x;

    // --- out[row, lane] = relu( sum_k x[k] * W_feat[k, lane] ) ---
    float o = 0.f;
    #pragma unroll
    for (int k4 = 0; k4 < 16; ++k4) {
        float4 xv = *(const float4*)&xs[w][k4 * 4];
        o = fmaf(xv.x, Wf[(k4 * 4 + 0) * NF + lane], o);
        o = fmaf(xv.y, Wf[(k4 * 4 + 1) * NF + lane], o);
        o = fmaf(xv.z, Wf[(k4 * 4 + 2) * NF + lane], o);
        o = fmaf(xv.w, Wf[(k4 * 4 + 3) * NF + lane], o);
    }
    out[(size_t)row * NF + lane] = fmaxf(o, 0.f);
}

extern "C" void kernel_launch(void* const* d_in, const int* in_sizes, int n_in,
                              void* d_out, int out_size, void* d_ws, size_t ws_size,
                              hipStream_t stream) {
    const float* nf  = (const float*)d_in[0];
    const float* adj = (const float*)d_in[1];
    const float* nrm = (const float*)d_in[2];
    const float* We  = (const float*)d_in[3];
    const float* Wf  = (const float*)d_in[4];
    float* out = (float*)d_out;

    kFused<<<ROWS / 4, 256, 0, stream>>>(nf, adj, nrm, We, Wf, out);
}